// Round 2
// baseline (1854.435 us; speedup 1.0000x reference)
//
#include <hip/hip_runtime.h>
#include <hip/hip_bf16.h>

#define N_NODES 50000
#define N_EDGES 800000
#define CLAMP_V 5.0f

typedef __hip_bfloat16 bf16;

__device__ __forceinline__ float b2f(bf16 v){ return __bfloat162float(v); }
__device__ __forceinline__ bf16 f2b(float v){ return __float2bfloat16(v); }
// order-preserving float->uint encoding for atomicMax; init 0 < any real key (scores >= -5)
__device__ __forceinline__ unsigned fenc(float f){ unsigned u=__float_as_uint(f); return (u&0x80000000u)? ~u : (u|0x80000000u); }
__device__ __forceinline__ float fdec(unsigned k){ unsigned u=(k&0x80000000u)? (k^0x80000000u) : ~k; return __uint_as_float(u); }

// dual-dtype load/store (flag is wave-uniform -> scalar branch)
__device__ __forceinline__ float ldin(const void* p, size_t i, bool f32){
  return f32 ? ((const float*)p)[i] : b2f(((const bf16*)p)[i]);
}
__device__ __forceinline__ void stout(void* p, size_t i, float v, bool f32){
  if(f32) ((float*)p)[i]=v; else ((bf16*)p)[i]=f2b(v);
}
__device__ __forceinline__ void* e_region(void* d_out, bool f32){
  return f32 ? (void*)((float*)d_out + (size_t)N_NODES*64)
             : (void*)((bf16*)d_out + (size_t)N_NODES*64);
}

// ---- workspace layout (fp32 word offsets). [0, W_ZEND) zeroed every launch. total 67.4 MB ----
#define W_FLAG  0          // 1 u32: 0=bf16 inputs, 1=f32 inputs
#define W_DEG   64         // N u32
#define W_M     50064      // N*8 u32 (encoded segment max)
#define W_DEN   450064     // N*8 f32
#define W_WV    850064     // N*64 f32
#define W_RV    4050064    // N*64 f32
#define W_ST    7250064    // 384 f32 stats: [0]=s1e,[64]=s2e,[128]=s1h,[192]=s2h,[256]=s1h2,[320]=s2h2
#define W_ZEND  7250448
#define W_QKV   7250448    // N*192 f32 [Q|K|V] col=h*8+d  (dead after edgeC)
#define W_HPRE  7250448    // N*64 f32 (reuses QKV region)
#define W_HSUM  10450448   // N*64 f32 (reuses QKV region)
#define W_END   16850448   // words

// ---------------- detect: bf16 vs f32 input encoding ----------------
__global__ void detect_kernel(const unsigned short* __restrict__ wq_raw, unsigned* __restrict__ flag){
  int t=threadIdx.x; int cnt=0;
  for(int i=t;i<4096;i+=64){
    unsigned e=(wq_raw[i]>>7)&0xFF;      // bf16 exponent field
    if(e>=130) cnt++;                    // |v|>=8 or inf/nan: impossible for real bf16 weights (sigma=0.1)
  }
  for(int o=32;o;o>>=1) cnt+=__shfl_down(cnt,o);
  if(t==0) *flag = (cnt>64)? 1u:0u;      // f32 data: low-half garbage -> cnt ~1000; bf16: 0
}

// ---------------- K0: QKV = x @ [Wq|Wk|Wv] (+bq on Q) ----------------
__global__ __launch_bounds__(256) void qkv_kernel(const void* __restrict__ x,
    const void* __restrict__ Wq, const void* __restrict__ bq,
    const void* __restrict__ Wk, const void* __restrict__ Wv,
    const unsigned* __restrict__ flagp, float* __restrict__ qkv)
{
  const bool f = (*flagp)!=0;
  __shared__ float sW[64*192];     // [k][j] j: 0-63 Q, 64-127 K, 128-191 V
  __shared__ float4 sxT[4][64];
  int t=threadIdx.x, wave=t>>6, lane=t&63;
  for (int i=t;i<64*64;i+=256){ int k=i>>6, j=i&63;
    sW[k*192+j]=ldin(Wq,i,f); sW[k*192+64+j]=ldin(Wk,i,f); sW[k*192+128+j]=ldin(Wv,i,f); }
  float bqv = ldin(bq,lane,f);
  __syncthreads();
  const int groups = N_NODES/16;   // 3125
  for (int g=blockIdx.x; g<groups; g+=gridDim.x){
    int n0 = g*16 + wave*4;
    float v0=ldin(x,(size_t)(n0+0)*64+lane,f);
    float v1=ldin(x,(size_t)(n0+1)*64+lane,f);
    float v2=ldin(x,(size_t)(n0+2)*64+lane,f);
    float v3=ldin(x,(size_t)(n0+3)*64+lane,f);
    sxT[wave][lane]=make_float4(v0,v1,v2,v3);
    __syncthreads();
    float aq[4]={0,0,0,0}, ak[4]={0,0,0,0}, av[4]={0,0,0,0};
    #pragma unroll 8
    for(int k=0;k<64;k++){
      float4 a = sxT[wave][k];
      float w0=sW[k*192+lane], w1=sW[k*192+64+lane], w2=sW[k*192+128+lane];
      aq[0]+=a.x*w0; aq[1]+=a.y*w0; aq[2]+=a.z*w0; aq[3]+=a.w*w0;
      ak[0]+=a.x*w1; ak[1]+=a.y*w1; ak[2]+=a.z*w1; ak[3]+=a.w*w1;
      av[0]+=a.x*w2; av[1]+=a.y*w2; av[2]+=a.z*w2; av[3]+=a.w*w2;
    }
    #pragma unroll
    for(int r=0;r<4;r++){
      int n=n0+r;
      qkv[n*192+lane]     = aq[r]+bqv;
      qkv[n*192+64+lane]  = ak[r];
      qkv[n*192+128+lane] = av[r];
    }
  }
}

// ---------------- K1: Ee GEMM + s + score + segment max + deg; s -> out e-region ----------------
__global__ __launch_bounds__(256) void edgeA_kernel(
    const void* __restrict__ edge_attr, const int* __restrict__ edge_index,
    const void* __restrict__ We, const void* __restrict__ be, const void* __restrict__ Aw,
    const float* __restrict__ qkv, const unsigned* __restrict__ flagp,
    unsigned* __restrict__ m_enc, unsigned* __restrict__ deg, void* __restrict__ d_out)
{
  const bool f = (*flagp)!=0;
  void* s_buf = e_region(d_out,f);
  __shared__ float sWW[64*64], sWB[64*64];   // permuted: lane c=(h,d) <-> We col h*16+d / h*16+8+d
  __shared__ float4 seaT[4][64];
  int t=threadIdx.x, wave=t>>6, lane=t&63;
  int h=lane>>3, d=lane&7;
  for(int i=t;i<64*64;i+=256){ int k=i>>6, c=i&63; int hh=c>>3, dd=c&7;
    sWW[i]=ldin(We,(size_t)k*128+hh*16+dd,f);
    sWB[i]=ldin(We,(size_t)k*128+hh*16+8+dd,f); }
  float beW=ldin(be,h*16+d,f), beB=ldin(be,h*16+8+d,f);
  float awv=ldin(Aw,d*8+h,f);      // Aw (Dh,H,1)
  __syncthreads();
  const int groups = N_EDGES/16;   // 50000
  for(int g=blockIdx.x; g<groups; g+=gridDim.x){
    int e0 = g*16 + wave*4;
    float v0=ldin(edge_attr,(size_t)(e0+0)*64+lane,f);
    float v1=ldin(edge_attr,(size_t)(e0+1)*64+lane,f);
    float v2=ldin(edge_attr,(size_t)(e0+2)*64+lane,f);
    float v3=ldin(edge_attr,(size_t)(e0+3)*64+lane,f);
    seaT[wave][lane]=make_float4(v0,v1,v2,v3);
    __syncthreads();
    float aW[4]={0,0,0,0}, aB[4]={0,0,0,0};
    #pragma unroll 8
    for(int k=0;k<64;k++){
      float4 a=seaT[wave][k];
      float wW=sWW[k*64+lane], wB=sWB[k*64+lane];
      aW[0]+=a.x*wW; aW[1]+=a.y*wW; aW[2]+=a.z*wW; aW[3]+=a.w*wW;
      aB[0]+=a.x*wB; aB[1]+=a.y*wB; aB[2]+=a.z*wB; aB[3]+=a.w*wB;
    }
    #pragma unroll
    for(int r=0;r<4;r++){
      int e=e0+r;
      int src=edge_index[e], dst=edge_index[N_EDGES+e];
      float Ew = aW[r]+beW;
      float Eb = aB[r]+beB;
      float kq = qkv[src*192+64+lane] + qkv[dst*192+lane];  // K[src]+Q[dst]
      float s1 = kq*Ew;
      float ss = (s1>=0.f) ? sqrtf(s1) : -sqrtf(-s1);       // signed sqrt
      float s2 = ss+Eb; s2 = s2>0.f ? s2 : 0.f;             // relu
      stout(s_buf,(size_t)e*64+lane,s2,f);
      float sc = s2*awv;
      sc += __shfl_xor(sc,1);
      sc += __shfl_xor(sc,2);
      sc += __shfl_xor(sc,4);     // sum over d within 8-lane group
      if(d==0){
        sc = fminf(fmaxf(sc,-CLAMP_V),CLAMP_V);
        atomicMax(&m_enc[dst*8+h], fenc(sc));
      }
      if(lane==0) atomicAdd(deg+dst,1u);
    }
  }
}

// ---------------- K2: denom = segment_sum(exp(score-m)); score recomputed from s ----------------
__global__ __launch_bounds__(256) void edgeB_kernel(const int* __restrict__ edge_index,
    const void* __restrict__ Aw, const unsigned* __restrict__ m_enc,
    const unsigned* __restrict__ flagp, void* __restrict__ d_out, float* __restrict__ denom)
{
  const bool f = (*flagp)!=0;
  const void* s_buf = e_region(d_out,f);
  int tid = blockIdx.x*256+threadIdx.x;  // E*8
  int e=tid>>3, hh=tid&7;
  float sc=0.f;
  #pragma unroll
  for(int dd=0;dd<8;dd++) sc += ldin(s_buf,(size_t)e*64+hh*8+dd,f)*ldin(Aw,dd*8+hh,f);
  sc = fminf(fmaxf(sc,-CLAMP_V),CLAMP_V);
  int dst=edge_index[N_EDGES+e];
  float m=fdec(m_enc[dst*8+hh]);
  atomicAdd(&denom[dst*8+hh], __expf(sc-m));
}

// ---------------- K3: wV/rowV scatter-accumulate; score recomputed via shfl ----------------
__global__ __launch_bounds__(256) void edgeC_kernel(const int* __restrict__ edge_index,
    const void* __restrict__ Aw, const unsigned* __restrict__ m_enc, const float* __restrict__ denom,
    const float* __restrict__ qkv, const unsigned* __restrict__ flagp, void* __restrict__ d_out,
    float* __restrict__ wV, float* __restrict__ rowV)
{
  const bool f = (*flagp)!=0;
  const void* s_buf = e_region(d_out,f);
  int tid=blockIdx.x*256+threadIdx.x;  // E*64
  int e=tid>>6, c=tid&63, hh=c>>3, dd=c&7;
  int src=edge_index[e], dst=edge_index[N_EDGES+e];
  float sval=ldin(s_buf,(size_t)e*64+c,f);
  float p = sval*ldin(Aw,dd*8+hh,f);
  p += __shfl_xor(p,1);
  p += __shfl_xor(p,2);
  p += __shfl_xor(p,4);                // score for (e,hh), all 8 lanes of group
  p = fminf(fmaxf(p,-CLAMP_V),CLAMP_V);
  float m=fdec(m_enc[dst*8+hh]);
  float den=denom[dst*8+hh];
  float attn=__expf(p-m)/(den+1e-16f);
  atomicAdd(&wV[dst*64+c], qkv[src*192+128+c]*attn);
  atomicAdd(&rowV[dst*64+c], sval*attn);
}

// ---------------- K4: e_pre = edge_attr + s @ WOe + bOe (in-place) + BN1e stats ----------------
__global__ __launch_bounds__(256) void edgeD_kernel(const void* __restrict__ edge_attr,
    const void* __restrict__ WOe, const void* __restrict__ bOe,
    const unsigned* __restrict__ flagp, void* __restrict__ d_out, float* __restrict__ stats)
{
  const bool f = (*flagp)!=0;
  void* e_io = e_region(d_out,f);
  __shared__ float sW[64*64];
  __shared__ float4 sTa[4][64], sTb[4][64];
  int t=threadIdx.x, wave=t>>6, lane=t&63;
  for(int i=t;i<64*64;i+=256) sW[i]=ldin(WOe,i,f);
  float bo=ldin(bOe,lane,f);
  float s1=0.f,s2=0.f;
  __syncthreads();
  const int groups=N_EDGES/32;   // 25000
  for(int g=blockIdx.x;g<groups;g+=gridDim.x){
    int e0=g*32+wave*8;
    float v[8];
    #pragma unroll
    for(int r=0;r<8;r++) v[r]=ldin(e_io,(size_t)(e0+r)*64+lane,f);
    sTa[wave][lane]=make_float4(v[0],v[1],v[2],v[3]);
    sTb[wave][lane]=make_float4(v[4],v[5],v[6],v[7]);
    __syncthreads();
    float acc[8]={0,0,0,0,0,0,0,0};
    #pragma unroll 8
    for(int k=0;k<64;k++){
      float4 a=sTa[wave][k], b=sTb[wave][k];
      float w=sW[k*64+lane];
      acc[0]+=a.x*w; acc[1]+=a.y*w; acc[2]+=a.z*w; acc[3]+=a.w*w;
      acc[4]+=b.x*w; acc[5]+=b.y*w; acc[6]+=b.z*w; acc[7]+=b.w*w;
    }
    #pragma unroll
    for(int r=0;r<8;r++){
      int e=e0+r;
      float ep=ldin(edge_attr,(size_t)e*64+lane,f)+bo+acc[r];
      stout(e_io,(size_t)e*64+lane,ep,f);
      s1+=ep; s2+=ep*ep;
    }
  }
  atomicAdd(&stats[lane], s1);
  atomicAdd(&stats[64+lane], s2);
}

// ---------------- K5: BN1e normalize (in-place) ----------------
__global__ __launch_bounds__(256) void edgeE_kernel(const unsigned* __restrict__ flagp,
    void* __restrict__ d_out, const float* __restrict__ stats,
    const void* __restrict__ g1e, const void* __restrict__ b1e)
{
  const bool f = (*flagp)!=0;
  void* e_io = e_region(d_out,f);
  size_t tid=(size_t)blockIdx.x*256+threadIdx.x;  // E*64
  int c=(int)(tid&63);
  float mu=stats[c]*(1.f/N_EDGES);
  float var=stats[64+c]*(1.f/N_EDGES)-mu*mu;
  float rs=rsqrtf(var+1e-5f);
  float val=ldin(e_io,tid,f);
  val=(val-mu)*rs*ldin(g1e,c,f)+ldin(b1e,c,f);
  stout(e_io,tid,val,f);
}

// ---------------- K6: node: rowV@VeRow + deg scaling + @WOh + residual + BN1h stats ----------------
__global__ __launch_bounds__(256) void h1_kernel(const float* __restrict__ wV, const float* __restrict__ rowV,
    const unsigned* __restrict__ deg, const void* __restrict__ VeRow, const void* __restrict__ deg_coef,
    const void* __restrict__ WOh, const void* __restrict__ bOh, const void* __restrict__ x,
    const unsigned* __restrict__ flagp, float* __restrict__ hpre, float* __restrict__ stats)
{
  const bool f = (*flagp)!=0;
  __shared__ float sW[64*64];
  __shared__ float4 sT[4][64];
  int t=threadIdx.x, wave=t>>6, lane=t&63;
  int hh=lane>>3, cc=lane&7;
  for(int i=t;i<64*64;i+=256) sW[i]=ldin(WOh,i,f);
  float ver[8];
  #pragma unroll
  for(int dd=0;dd<8;dd++) ver[dd]=ldin(VeRow,(dd*8+hh)*8+cc,f);  // VeRow (Dh,H,Dh)
  float dc0=ldin(deg_coef,lane*2,f), dc1=ldin(deg_coef,lane*2+1,f);
  float bo=ldin(bOh,lane,f);
  float s1=0.f,s2=0.f;
  __syncthreads();
  const int groups=N_NODES/16;
  for(int g=blockIdx.x;g<groups;g+=gridDim.x){
    int n0=g*16+wave*4;
    float hv[4];
    #pragma unroll
    for(int r=0;r<4;r++){
      int n=n0+r;
      const float4* rp=(const float4*)&rowV[n*64+hh*8];
      float4 ra=rp[0], rb=rp[1];
      float rvp=ra.x*ver[0]+ra.y*ver[1]+ra.z*ver[2]+ra.w*ver[3]
               +rb.x*ver[4]+rb.y*ver[5]+rb.z*ver[6]+rb.w*ver[7];
      float wv=wV[n*64+lane]+rvp;
      float ld=__logf((float)deg[n]+1.f);
      hv[r]=wv*(dc0+ld*dc1);
    }
    sT[wave][lane]=make_float4(hv[0],hv[1],hv[2],hv[3]);
    __syncthreads();
    float acc[4]={0,0,0,0};
    #pragma unroll 8
    for(int k=0;k<64;k++){
      float4 a=sT[wave][k]; float w=sW[k*64+lane];
      acc[0]+=a.x*w; acc[1]+=a.y*w; acc[2]+=a.z*w; acc[3]+=a.w*w;
    }
    #pragma unroll
    for(int r=0;r<4;r++){
      int n=n0+r;
      float hp=ldin(x,(size_t)n*64+lane,f)+bo+acc[r];
      hpre[n*64+lane]=hp;
      s1+=hp; s2+=hp*hp;
    }
  }
  atomicAdd(&stats[128+lane],s1);
  atomicAdd(&stats[192+lane],s2);
}

// ---------------- K7: BN1h apply + FFN + residual + BN2h stats ----------------
__global__ __launch_bounds__(256) void h2_kernel(const float* __restrict__ hpre,
    const void* __restrict__ W1, const void* __restrict__ b1, const void* __restrict__ W2, const void* __restrict__ b2,
    const void* __restrict__ g1h, const void* __restrict__ be1h,
    const unsigned* __restrict__ flagp, float* __restrict__ hsum, float* __restrict__ stats)
{
  const bool f = (*flagp)!=0;
  __shared__ float sW1[64*128];
  __shared__ float4 shT[4][64];
  __shared__ float4 stT[4][128];
  int t=threadIdx.x, wave=t>>6, lane=t&63;
  for(int i=t;i<64*128;i+=256) sW1[i]=ldin(W1,i,f);
  float mu=stats[128+lane]*(1.f/N_NODES);
  float var=stats[192+lane]*(1.f/N_NODES)-mu*mu;
  float rs=rsqrtf(var+1e-5f);
  float gg=ldin(g1h,lane,f), bb=ldin(be1h,lane,f);
  float b1a=ldin(b1,lane,f), b1b=ldin(b1,64+lane,f);
  float b2c=ldin(b2,lane,f);
  float s1=0.f,s2=0.f;
  __syncthreads();
  const int groups=N_NODES/16;
  for(int g=blockIdx.x;g<groups;g+=gridDim.x){
    int n0=g*16+wave*4;
    float h1v[4];
    #pragma unroll
    for(int r=0;r<4;r++) h1v[r]=(hpre[(n0+r)*64+lane]-mu)*rs*gg+bb;
    shT[wave][lane]=make_float4(h1v[0],h1v[1],h1v[2],h1v[3]);
    __syncthreads();
    float t0[4]={0,0,0,0}, t1[4]={0,0,0,0};
    #pragma unroll 8
    for(int k=0;k<64;k++){
      float4 a=shT[wave][k];
      float w0=sW1[k*128+lane], w1=sW1[k*128+64+lane];
      t0[0]+=a.x*w0; t0[1]+=a.y*w0; t0[2]+=a.z*w0; t0[3]+=a.w*w0;
      t1[0]+=a.x*w1; t1[1]+=a.y*w1; t1[2]+=a.z*w1; t1[3]+=a.w*w1;
    }
    #pragma unroll
    for(int r=0;r<4;r++){ t0[r]=fmaxf(t0[r]+b1a,0.f); t1[r]=fmaxf(t1[r]+b1b,0.f); }
    stT[wave][lane]=make_float4(t0[0],t0[1],t0[2],t0[3]);
    stT[wave][64+lane]=make_float4(t1[0],t1[1],t1[2],t1[3]);
    __syncthreads();
    float acc[4]={0,0,0,0};
    #pragma unroll 8
    for(int k=0;k<128;k++){
      float4 a=stT[wave][k];
      float w=ldin(W2,(size_t)k*64+lane,f);
      acc[0]+=a.x*w; acc[1]+=a.y*w; acc[2]+=a.z*w; acc[3]+=a.w*w;
    }
    #pragma unroll
    for(int r=0;r<4;r++){
      float hs=h1v[r]+acc[r]+b2c;
      hsum[(n0+r)*64+lane]=hs;
      s1+=hs; s2+=hs*hs;
    }
  }
  atomicAdd(&stats[256+lane],s1);
  atomicAdd(&stats[320+lane],s2);
}

// ---------------- K8: BN2h normalize -> h output ----------------
__global__ __launch_bounds__(256) void h3_kernel(const float* __restrict__ hsum,
    const float* __restrict__ stats, const void* __restrict__ g2h, const void* __restrict__ b2h,
    const unsigned* __restrict__ flagp, void* __restrict__ d_out)
{
  const bool f = (*flagp)!=0;
  int tid=blockIdx.x*256+threadIdx.x;  // N*64
  int c=tid&63;
  float mu=stats[256+c]*(1.f/N_NODES);
  float var=stats[320+c]*(1.f/N_NODES)-mu*mu;
  float rs=rsqrtf(var+1e-5f);
  float val=(hsum[tid]-mu)*rs*ldin(g2h,c,f)+ldin(b2h,c,f);
  stout(d_out,tid,val,f);
}

extern "C" void kernel_launch(void* const* d_in, const int* in_sizes, int n_in,
                              void* d_out, int out_size, void* d_ws, size_t ws_size,
                              hipStream_t stream)
{
  const void* x        =d_in[0];
  const void* edge_attr=d_in[1];
  const int*  edge_index=(const int*)d_in[2];
  const void* Wq =d_in[3];
  const void* bq =d_in[4];
  const void* Wk =d_in[5];
  const void* We =d_in[6];
  const void* be =d_in[7];
  const void* Wv =d_in[8];
  const void* Aw =d_in[9];
  const void* VeRow=d_in[10];
  const void* deg_coef=d_in[11];
  const void* WOh=d_in[12];
  const void* bOh=d_in[13];
  const void* WOe=d_in[14];
  const void* bOe=d_in[15];
  const void* g1h=d_in[16];
  const void* be1h=d_in[17];
  const void* g1e=d_in[18];
  const void* be1e=d_in[19];
  const void* W1 =d_in[20];
  const void* b1 =d_in[21];
  const void* W2 =d_in[22];
  const void* b2 =d_in[23];
  const void* g2h=d_in[24];
  const void* be2h=d_in[25];

  float* ws=(float*)d_ws;
  unsigned* flag =(unsigned*)(ws+W_FLAG);
  unsigned* deg  =(unsigned*)(ws+W_DEG);
  unsigned* m_enc=(unsigned*)(ws+W_M);
  float* denom=ws+W_DEN;
  float* wV   =ws+W_WV;
  float* rowV =ws+W_RV;
  float* stats=ws+W_ST;
  float* qkv  =ws+W_QKV;
  float* hpre =ws+W_HPRE;
  float* hsum =ws+W_HSUM;

  hipMemsetAsync(d_ws,0,(size_t)W_ZEND*4,stream);
  hipLaunchKernelGGL(detect_kernel,dim3(1),dim3(64),0,stream,(const unsigned short*)Wq,flag);
  hipLaunchKernelGGL(qkv_kernel,  dim3(1024),  dim3(256),0,stream, x,Wq,bq,Wk,Wv,flag,qkv);
  hipLaunchKernelGGL(edgeA_kernel,dim3(1024),  dim3(256),0,stream, edge_attr,edge_index,We,be,Aw,qkv,flag,m_enc,deg,d_out);
  hipLaunchKernelGGL(edgeB_kernel,dim3(25000), dim3(256),0,stream, edge_index,Aw,m_enc,flag,d_out,denom);
  hipLaunchKernelGGL(edgeC_kernel,dim3(200000),dim3(256),0,stream, edge_index,Aw,m_enc,denom,qkv,flag,d_out,wV,rowV);
  hipLaunchKernelGGL(edgeD_kernel,dim3(1024),  dim3(256),0,stream, edge_attr,WOe,bOe,flag,d_out,stats);
  hipLaunchKernelGGL(edgeE_kernel,dim3(200000),dim3(256),0,stream, flag,d_out,stats,g1e,be1e);
  hipLaunchKernelGGL(h1_kernel,   dim3(1024),  dim3(256),0,stream, wV,rowV,deg,VeRow,deg_coef,WOh,bOh,x,flag,hpre,stats);
  hipLaunchKernelGGL(h2_kernel,   dim3(1024),  dim3(256),0,stream, hpre,W1,b1,W2,b2,g1h,be1h,flag,hsum,stats);
  hipLaunchKernelGGL(h3_kernel,   dim3(12500), dim3(256),0,stream, hsum,stats,g2h,be2h,flag,d_out);
}